// Round 15
// baseline (63.008 us; speedup 1.0000x reference)
//
#include <hip/hip_runtime.h>
#include <hip/hip_bf16.h>

#define NH 4
#define HD 32
#define PAD 3
#define HW 56
#define NPIX (8*HW*HW)          // 25088 pixels
#define SCALE 0.17677669529663687f

// ---------------- workspace layout (bytes) ----------------
// qs    : bf16 [8][4][56][56][32]    6,422,528  (q, pre-scaled, bf16)
// kbuf  : bf16 [8][4][56][56][32]    6,422,528
// vbuf  : bf16 [8][4][56][56][32]    6,422,528
// xh/xl : bf16 [25088][128]          6,422,528 each   (attn_h/attn_l from natt)
// W splits: qkv hi/lo 98,304 each; proj hi/lo 32,768 each
#define QS_OFF   0
#define K_OFF    12845056
#define V_OFF    (K_OFF + 6422528)
#define XH_OFF   (V_OFF + 6422528)      // attn_h (written by natt)
#define XL_OFF   (XH_OFF + 6422528)     // attn_l
#define WQH_OFF  (XL_OFF + 6422528)
#define WQL_OFF  (WQH_OFF + 98304)
#define WPH_OFF  (WQL_OFF + 98304)
#define WPL_OFF  (WPH_OFF + 32768)

typedef __attribute__((ext_vector_type(8))) short short8v;
typedef __attribute__((ext_vector_type(4))) float f32x4;

__device__ __forceinline__ float blo(unsigned u) { return __uint_as_float(u << 16); }
__device__ __forceinline__ float bhi(unsigned u) { return __uint_as_float(u & 0xffff0000u); }

__device__ __forceinline__ unsigned short f2b(float x) {       // f32 -> bf16 bits, RNE
    unsigned u = __float_as_uint(x);
    unsigned r = (u + 0x7fffu + ((u >> 16) & 1u)) >> 16;
    return (unsigned short)r;
}
__device__ __forceinline__ float b2f(unsigned short s) { return __uint_as_float((unsigned)s << 16); }

// two 4-length fma chains + final add (round-9 order)
__device__ __forceinline__ float dot8v(const float* q8, uint4 k) {
    float s0, s1;
    s0 = q8[0] * blo(k.x); s0 = fmaf(q8[1], bhi(k.x), s0);
    s0 = fmaf(q8[2], blo(k.y), s0); s0 = fmaf(q8[3], bhi(k.y), s0);
    s1 = q8[4] * blo(k.z); s1 = fmaf(q8[5], bhi(k.z), s1);
    s1 = fmaf(q8[6], blo(k.w), s1); s1 = fmaf(q8[7], bhi(k.w), s1);
    return s0 + s1;
}

// quad (4-lane) sum via DPP quad_perm: xor1 = 0xB1, xor2 = 0x4E. VALU-only.
__device__ __forceinline__ float quad_sum(float x) {
    x += __int_as_float(__builtin_amdgcn_update_dpp(0, __float_as_int(x), 0xB1, 0xF, 0xF, true));
    x += __int_as_float(__builtin_amdgcn_update_dpp(0, __float_as_int(x), 0x4E, 0xF, 0xF, true));
    return x;
}

// ---------------------------------------------------------------------------
// Pre-split (weights only): W_qkv 12288 f4 + W_proj 4096 f4 = 16384.
// (Round-13 lesson: folding this into gemm B-staging re-does the split
//  392x6 times and regresses; keep it as one tiny dispatch.)
// ---------------------------------------------------------------------------
__global__ __launch_bounds__(256) void split_k(
    const float* __restrict__ wq, const float* __restrict__ wp,
    unsigned short* __restrict__ wqh, unsigned short* __restrict__ wql,
    unsigned short* __restrict__ wph, unsigned short* __restrict__ wpl)
{
    int idx = blockIdx.x * 256 + threadIdx.x;
    if (idx >= 16384) return;
    const float* src; unsigned short *dh, *dl; int off;
    if (idx < 12288) { src = wq; dh = wqh; dl = wql; off = idx; }
    else             { src = wp; dh = wph; dl = wpl; off = idx - 12288; }
    float4 v = ((const float4*)src)[off];
    ushort4 h, l;
    h.x = f2b(v.x); l.x = f2b(v.x - b2f(h.x));
    h.y = f2b(v.y); l.y = f2b(v.y - b2f(h.y));
    h.z = f2b(v.z); l.z = f2b(v.z - b2f(h.z));
    h.w = f2b(v.w); l.w = f2b(v.w - b2f(h.w));
    ((ushort4*)dh)[off] = h;
    ((ushort4*)dl)[off] = l;
}

// ---------------------------------------------------------------------------
// Fused-N MFMA GEMM (bf16x2 split), grid-balanced:
// grid = (392 m-blocks, NB n-groups); each block stages its A-tile once and
// runs NPH n-phases (n0 = (blockIdx.y*NPH + ph)*64).
//   QKV: NB=2, NPH=3 -> 784 blocks = 3.06/CU (was 392 = 1.53/CU: half the
//        CUs ran 2 sequential blocks -> ~2x makespan). A read 2x (min 1x,
//        old fused 1x but unbalanced; pre-round-7 was 6x).
//   proj: NB=2, NPH=1 -> 784 blocks.
//  SELQKV=1: q/k/v scatter epilogue (q bf16 pre-scaled), A = f32 x split
//            in-kernel.  SELQKV=0: f32 rows, A = attn hi/lo bf16 from natt.
// acc = Ah*Bh + Ah*Bl + Al*Bh per fragment, mfma_f32_16x16x32_bf16.
// LDS 64 KB, XOR swizzle byte ^= (row&7)<<4 -> conflict-free b128 reads.
// ---------------------------------------------------------------------------
template <int SELQKV, int NPH>
__global__ __launch_bounds__(256, 2) void gemm_fused(
    const float* __restrict__ Af32,
    const unsigned short* __restrict__ Axh, const unsigned short* __restrict__ Axl,
    const unsigned short* __restrict__ Bgh, const unsigned short* __restrict__ Bgl,
    const float* __restrict__ bias,
    unsigned short* __restrict__ outq, unsigned short* __restrict__ outk,
    unsigned short* __restrict__ outv, float* __restrict__ outp)
{
    __shared__ unsigned short sAh[64 * 128];
    __shared__ unsigned short sAl[64 * 128];
    __shared__ unsigned short sBh[64 * 128];
    __shared__ unsigned short sBl[64 * 128];

    const int tid = threadIdx.x;
    const int m0 = blockIdx.x * 64;
    const int nbase = blockIdx.y * NPH;

    // ---- stage A once per block ----
    if constexpr (SELQKV) {
#pragma unroll
        for (int it = 0; it < 8; ++it) {
            int idx = tid + it * 256;          // 0..2047 float4 chunks
            int row = idx >> 5;                // 0..63
            int c4  = idx & 31;
            float4 a = *(const float4*)(Af32 + (size_t)(m0 + row) * 128 + c4 * 4);
            int byte = (row * 256 + c4 * 8) ^ ((row & 7) << 4);
            ushort4 h, l;
            h.x = f2b(a.x); l.x = f2b(a.x - b2f(h.x));
            h.y = f2b(a.y); l.y = f2b(a.y - b2f(h.y));
            h.z = f2b(a.z); l.z = f2b(a.z - b2f(h.z));
            h.w = f2b(a.w); l.w = f2b(a.w - b2f(h.w));
            *(ushort4*)((char*)sAh + byte) = h;
            *(ushort4*)((char*)sAl + byte) = l;
        }
    } else {
#pragma unroll
        for (int it = 0; it < 4; ++it) {
            int chunk = it * 256 + tid;        // 0..1023
            int row = chunk >> 4, c16 = chunk & 15;
            int byte = (row * 256 + c16 * 16) ^ ((row & 7) << 4);
            size_t ga = (size_t)(m0 + row) * 128 + c16 * 8;
            *(uint4*)((char*)sAh + byte) = *(const uint4*)(Axh + ga);
            *(uint4*)((char*)sAl + byte) = *(const uint4*)(Axl + ga);
        }
    }

    const int lane = tid & 63;
    const int w  = tid >> 6;
    const int wr = w >> 1, wc = w & 1;       // 2x2 waves -> 64x64
    const int fr  = lane & 15;
    const int kqb = (lane >> 4) * 16;        // k byte offset within 64B group
    const int cl = lane & 15;
    const int rq = lane >> 4;

#pragma unroll
    for (int ph = 0; ph < NPH; ++ph) {
        const int n0 = (nbase + ph) * 64;
        if (ph > 0) __syncthreads();         // prior mfma reads done before B overwrite
#pragma unroll
        for (int it = 0; it < 4; ++it) {
            int chunk = it * 256 + tid;      // 0..1023
            int row = chunk >> 4, c16 = chunk & 15;
            int byte = (row * 256 + c16 * 16) ^ ((row & 7) << 4);
            size_t gb = (size_t)(n0 + row) * 128 + c16 * 8;
            *(uint4*)((char*)sBh + byte) = *(const uint4*)(Bgh + gb);
            *(uint4*)((char*)sBl + byte) = *(const uint4*)(Bgl + gb);
        }
        __syncthreads();

        f32x4 acc[2][2];
#pragma unroll
        for (int i = 0; i < 2; ++i)
#pragma unroll
            for (int j = 0; j < 2; ++j) acc[i][j] = (f32x4){0.f, 0.f, 0.f, 0.f};

#pragma unroll
        for (int ks = 0; ks < 4; ++ks) {
            short8v ah[2], al[2], bh[2], bl[2];
#pragma unroll
            for (int mi = 0; mi < 2; ++mi) {
                int row = wr * 32 + mi * 16 + fr;
                int byte = (row * 256 + ks * 64 + kqb) ^ ((row & 7) << 4);
                ah[mi] = *(const short8v*)((const char*)sAh + byte);
                al[mi] = *(const short8v*)((const char*)sAl + byte);
            }
#pragma unroll
            for (int ni = 0; ni < 2; ++ni) {
                int row = wc * 32 + ni * 16 + fr;
                int byte = (row * 256 + ks * 64 + kqb) ^ ((row & 7) << 4);
                bh[ni] = *(const short8v*)((const char*)sBh + byte);
                bl[ni] = *(const short8v*)((const char*)sBl + byte);
            }
#pragma unroll
            for (int mi = 0; mi < 2; ++mi)
#pragma unroll
                for (int ni = 0; ni < 2; ++ni) {
                    acc[mi][ni] = __builtin_amdgcn_mfma_f32_16x16x32_bf16(ah[mi], bh[ni], acc[mi][ni], 0, 0, 0);
                    acc[mi][ni] = __builtin_amdgcn_mfma_f32_16x16x32_bf16(ah[mi], bl[ni], acc[mi][ni], 0, 0, 0);
                    acc[mi][ni] = __builtin_amdgcn_mfma_f32_16x16x32_bf16(al[mi], bh[ni], acc[mi][ni], 0, 0, 0);
                }
        }

        // ---- epilogue: C/D layout col=lane&15, row=4*(lane>>4)+reg ----
#pragma unroll
        for (int mi = 0; mi < 2; ++mi) {
#pragma unroll
            for (int reg = 0; reg < 4; ++reg) {
                int m = m0 + wr * 32 + mi * 16 + rq * 4 + reg;
                if constexpr (SELQKV) {
                    int b = m / 3136;
                    int r = m - b * 3136;
                    int y = r / 56;
                    int x = r - y * 56;
#pragma unroll
                    for (int ni = 0; ni < 2; ++ni) {
                        int nn = n0 + wc * 32 + ni * 16 + cl;   // 0..383
                        float val = acc[mi][ni][reg] + bias[nn];
                        int sel = nn >> 7;                      // 0=q 1=k 2=v
                        int nl = nn & 127;
                        int h = nl >> 5, d = nl & 31;
                        size_t oi = ((size_t)((b * NH + h) * 3136) + y * 56 + x) * 32 + d;
                        if (sel == 0)      outq[oi] = f2b(val * SCALE);   // q bf16
                        else if (sel == 1) outk[oi] = f2b(val);
                        else               outv[oi] = f2b(val);
                    }
                } else {
#pragma unroll
                    for (int ni = 0; ni < 2; ++ni) {
                        int nn = n0 + wc * 32 + ni * 16 + cl;
                        outp[(size_t)m * 128 + nn] = acc[mi][ni][reg] + bias[nn];
                    }
                }
            }
        }
    }
}

// ---------------------------------------------------------------------------
// Neighborhood attention v6b (round-14 version, unchanged — best measured):
// 4 threads per (pixel,head) d-chunk split, 256 thr, 8x8 tile, halo 14x14,
// grid 49x4x8.  V unpacked to f32 in LDS at staging (PV axpy = plain fmaf);
// K bf16 [pix][c]; dot as two 4-chains + add; q bf16 load hoisted (16B).
// LDS 36.8 KB -> 4 blocks/CU = 16 waves/CU.
// ---------------------------------------------------------------------------
__global__ __launch_bounds__(256, 4) void natt_k(
    const unsigned short* __restrict__ qs, const unsigned short* __restrict__ kb,
    const unsigned short* __restrict__ vb, const float* __restrict__ rpb,
    unsigned short* __restrict__ attn_h, unsigned short* __restrict__ attn_l)
{
    __shared__ uint4 ks[196 * 4];                    // K bf16 [pix][c], 12544 B
    __shared__ __align__(16) float vfs[4][1572];     // V f32 c-sections, 25152 B

    const int tid = threadIdx.x;
    const int b = blockIdx.z, h = blockIdx.y;
    const int tyy = blockIdx.x / 7, txx = blockIdx.x - tyy * 7;  // 7x7 tiles
    const int y0 = tyy * 8, x0 = txx * 8;
    const int bh = b * NH + h;

    const int p = tid >> 2, c = tid & 3;   // quads 4-aligned -> DPP partners co-active
    const int py = p >> 3;
    const int pxx = p & 7;

    // hoisted q load (bf16, 16B) — unpack once per thread
    float q[8];
    {
        uint4 qv = *(const uint4*)(qs +
            ((size_t)(bh * 3136) + (y0 + py) * 56 + (x0 + pxx)) * 32 + c * 8);
        q[0] = blo(qv.x); q[1] = bhi(qv.x); q[2] = blo(qv.y); q[3] = bhi(qv.y);
        q[4] = blo(qv.z); q[5] = bhi(qv.z); q[6] = blo(qv.w); q[7] = bhi(qv.w);
    }

    const uint4* kg = (const uint4*)kb;  // 4 uint4 per pixel (32 bf16)
    const uint4* vg = (const uint4*)vb;
    for (int idx = tid; idx < 784; idx += 256) {   // 196 pix * 4 chunks
        int pix = idx >> 2, cc = idx & 3;
        int i = pix / 14;
        int j = pix - i * 14;
        int y = y0 + i - PAD;
        int x = x0 + j - PAD;
        uint4 zk = make_uint4(0u, 0u, 0u, 0u);
        uint4 zv = make_uint4(0u, 0u, 0u, 0u);
        if ((unsigned)y < 56u && (unsigned)x < 56u) {
            int g = ((bh * 3136) + y * 56 + x) * 4 + cc;
            zk = kg[g];
            zv = vg[g];
        }
        ks[idx] = zk;
        float4 f0, f1;
        f0.x = blo(zv.x); f0.y = bhi(zv.x); f0.z = blo(zv.y); f0.w = bhi(zv.y);
        f1.x = blo(zv.z); f1.y = bhi(zv.z); f1.z = blo(zv.w); f1.w = bhi(zv.w);
        float* vd = &vfs[cc][pix * 8];
        *(float4*)(vd)     = f0;
        *(float4*)(vd + 4) = f1;
    }
    __syncthreads();

    float acc[8];
#pragma unroll
    for (int d = 0; d < 8; ++d) acc[d] = 0.f;
    float l = 0.f;

    const float* rph = rpb + h * 49;       // uniform index -> scalar loads
    const float* vbase = &vfs[c][0];

#pragma unroll
    for (int dy = 0; dy < 7; ++dy) {
        int rowpix = (py + dy) * 14 + pxx;
#pragma unroll
        for (int dx = 0; dx < 7; ++dx) {
            int pix = rowpix + dx;
            float s  = dot8v(q, ks[pix * 4 + c]);
            float sf = quad_sum(s) + rph[dy * 7 + dx];
            float e  = __expf(sf);
            l += e;
            const float* vv = vbase + pix * 8;
            float4 v0 = *(const float4*)(vv);
            float4 v1 = *(const float4*)(vv + 4);
            acc[0] = fmaf(e, v0.x, acc[0]); acc[1] = fmaf(e, v0.y, acc[1]);
            acc[2] = fmaf(e, v0.z, acc[2]); acc[3] = fmaf(e, v0.w, acc[3]);
            acc[4] = fmaf(e, v1.x, acc[4]); acc[5] = fmaf(e, v1.y, acc[5]);
            acc[6] = fmaf(e, v1.z, acc[6]); acc[7] = fmaf(e, v1.w, acc[7]);
        }
    }

    float rl = 1.0f / l;

    // pack 8 dims -> (hi, lo) bf16 uint4, single b128 store each
    unsigned short hv[8], lv[8];
#pragma unroll
    for (int d = 0; d < 8; ++d) {
        float val = acc[d] * rl;
        hv[d] = f2b(val);
        lv[d] = f2b(val - b2f(hv[d]));
    }
    uint4 uh, ul;
    uh.x = (unsigned)hv[0] | ((unsigned)hv[1] << 16);
    uh.y = (unsigned)hv[2] | ((unsigned)hv[3] << 16);
    uh.z = (unsigned)hv[4] | ((unsigned)hv[5] << 16);
    uh.w = (unsigned)hv[6] | ((unsigned)hv[7] << 16);
    ul.x = (unsigned)lv[0] | ((unsigned)lv[1] << 16);
    ul.y = (unsigned)lv[2] | ((unsigned)lv[3] << 16);
    ul.z = (unsigned)lv[4] | ((unsigned)lv[5] << 16);
    ul.w = (unsigned)lv[6] | ((unsigned)lv[7] << 16);

    size_t base = ((size_t)(b * 3136) + (y0 + py) * 56 + (x0 + pxx)) * 128 + h * 32 + c * 8;
    *(uint4*)(attn_h + base) = uh;
    *(uint4*)(attn_l + base) = ul;
}

extern "C" void kernel_launch(void* const* d_in, const int* in_sizes, int n_in,
                              void* d_out, int out_size, void* d_ws, size_t ws_size,
                              hipStream_t stream)
{
    const float* x     = (const float*)d_in[0];
    const float* Wqkv  = (const float*)d_in[1];
    const float* bqkv  = (const float*)d_in[2];
    const float* rpb   = (const float*)d_in[3];
    const float* Wproj = (const float*)d_in[4];
    const float* bproj = (const float*)d_in[5];
    float* out = (float*)d_out;

    char* ws = (char*)d_ws;
    unsigned short* qsb  = (unsigned short*)(ws + QS_OFF);   // q bf16 (pre-scaled)
    unsigned short* kbuf = (unsigned short*)(ws + K_OFF);
    unsigned short* vbuf = (unsigned short*)(ws + V_OFF);
    unsigned short* xh   = (unsigned short*)(ws + XH_OFF);   // attn_h (from natt)
    unsigned short* xl   = (unsigned short*)(ws + XL_OFF);   // attn_l
    unsigned short* wqh  = (unsigned short*)(ws + WQH_OFF);
    unsigned short* wql  = (unsigned short*)(ws + WQL_OFF);
    unsigned short* wph  = (unsigned short*)(ws + WPH_OFF);
    unsigned short* wpl  = (unsigned short*)(ws + WPL_OFF);

    // 0) split weights into (hi,lo) bf16 (tiny)
    split_k<<<64, 256, 0, stream>>>(Wqkv, Wproj, wqh, wql, wph, wpl);

    // 1) QKV projection: (392 m, 2 n-groups) x NPH=3 -> 784 blocks = 3.06/CU
    gemm_fused<1, 3><<<dim3(392, 2), 256, 0, stream>>>(
        x, nullptr, nullptr, wqh, wql, bqkv, qsb, kbuf, vbuf, nullptr);

    // 2) neighborhood attention (v6b): 49 tiles x 4 heads x 8 batch, 256 thr
    natt_k<<<dim3(49, NH, 8), 256, 0, stream>>>(qsb, kbuf, vbuf, rpb, xh, xl);

    // 3) output projection: (392 m, 2 n-groups) x NPH=1 -> 784 blocks
    gemm_fused<0, 1><<<dim3(392, 2), 256, 0, stream>>>(
        nullptr, xh, xl, wph, wpl, bproj, nullptr, nullptr, nullptr, (float*)d_out);
}

// Round 16
// 58.245 us; speedup vs baseline: 1.0818x; 1.0818x over previous
//
#include <hip/hip_runtime.h>
#include <hip/hip_bf16.h>

#define NH 4
#define HD 32
#define PAD 3
#define HW 56
#define NPIX (8*HW*HW)          // 25088 pixels
#define SCALE 0.17677669529663687f

// ---------------- workspace layout (bytes) ----------------
// qs    : bf16 [8][4][56][56][32]    6,422,528  (q, pre-scaled, bf16)
// kbuf  : bf16 [8][4][56][56][32]    6,422,528
// vbuf  : bf16 [8][4][56][56][32]    6,422,528
// xh    : bf16 [25088][128]          6,422,528  (attn bf16 from natt)
// W splits: qkv hi/lo 98,304 each; proj hi/lo 32,768 each
#define QS_OFF   0
#define K_OFF    12845056
#define V_OFF    (K_OFF + 6422528)
#define XH_OFF   (V_OFF + 6422528)      // attn (written by natt)
#define XL_OFF   (XH_OFF + 6422528)     // (unused now)
#define WQH_OFF  (XL_OFF + 6422528)
#define WQL_OFF  (WQH_OFF + 98304)
#define WPH_OFF  (WQL_OFF + 98304)
#define WPL_OFF  (WPH_OFF + 32768)

typedef __attribute__((ext_vector_type(8))) short short8v;
typedef __attribute__((ext_vector_type(4))) float f32x4;

__device__ __forceinline__ float blo(unsigned u) { return __uint_as_float(u << 16); }
__device__ __forceinline__ float bhi(unsigned u) { return __uint_as_float(u & 0xffff0000u); }

__device__ __forceinline__ unsigned short f2b(float x) {       // f32 -> bf16 bits, RNE
    unsigned u = __float_as_uint(x);
    unsigned r = (u + 0x7fffu + ((u >> 16) & 1u)) >> 16;
    return (unsigned short)r;
}
__device__ __forceinline__ float b2f(unsigned short s) { return __uint_as_float((unsigned)s << 16); }

// two 4-length fma chains + final add (round-9 order)
__device__ __forceinline__ float dot8v(const float* q8, uint4 k) {
    float s0, s1;
    s0 = q8[0] * blo(k.x); s0 = fmaf(q8[1], bhi(k.x), s0);
    s0 = fmaf(q8[2], blo(k.y), s0); s0 = fmaf(q8[3], bhi(k.y), s0);
    s1 = q8[4] * blo(k.z); s1 = fmaf(q8[5], bhi(k.z), s1);
    s1 = fmaf(q8[6], blo(k.w), s1); s1 = fmaf(q8[7], bhi(k.w), s1);
    return s0 + s1;
}

// quad (4-lane) sum via DPP quad_perm: xor1 = 0xB1, xor2 = 0x4E. VALU-only.
__device__ __forceinline__ float quad_sum(float x) {
    x += __int_as_float(__builtin_amdgcn_update_dpp(0, __float_as_int(x), 0xB1, 0xF, 0xF, true));
    x += __int_as_float(__builtin_amdgcn_update_dpp(0, __float_as_int(x), 0x4E, 0xF, 0xF, true));
    return x;
}

// ---------------------------------------------------------------------------
// Pre-split (weights only): W_qkv 12288 f4 + W_proj 4096 f4 = 16384.
// ---------------------------------------------------------------------------
__global__ __launch_bounds__(256) void split_k(
    const float* __restrict__ wq, const float* __restrict__ wp,
    unsigned short* __restrict__ wqh, unsigned short* __restrict__ wql,
    unsigned short* __restrict__ wph, unsigned short* __restrict__ wpl)
{
    int idx = blockIdx.x * 256 + threadIdx.x;
    if (idx >= 16384) return;
    const float* src; unsigned short *dh, *dl; int off;
    if (idx < 12288) { src = wq; dh = wqh; dl = wql; off = idx; }
    else             { src = wp; dh = wph; dl = wpl; off = idx - 12288; }
    float4 v = ((const float4*)src)[off];
    ushort4 h, l;
    h.x = f2b(v.x); l.x = f2b(v.x - b2f(h.x));
    h.y = f2b(v.y); l.y = f2b(v.y - b2f(h.y));
    h.z = f2b(v.z); l.z = f2b(v.z - b2f(h.z));
    h.w = f2b(v.w); l.w = f2b(v.w - b2f(h.w));
    ((ushort4*)dh)[off] = h;
    ((ushort4*)dl)[off] = l;
}

// ---------------------------------------------------------------------------
// Fused-N MFMA GEMM, round-14 structure (392 m-blocks, A staged once, NPH
// internal n-phases restaging the 32 KB pre-split B-tile).
//  SELQKV=1: NPH=6, A = f32 x split hi/lo in-kernel; acc = AhBh+AhBl+AlBh
//            (bf16x2); q/k/v scatter epilogue (q bf16 pre-scaled).
//  SELQKV=0: NPH=2, A = attn SINGLE bf16 (accuracy analysis: attn bf16
//            quantization adds ~1e-4 to output, inside 8.8e-4 threshold);
//            acc = Ah*Bh + Ah*Bl (2 MFMA/frag). LDS 48 KB -> 3 blocks/CU.
// LDS XOR swizzle byte ^= (row&7)<<4 -> conflict-free b128 reads.
// ---------------------------------------------------------------------------
template <int SELQKV>
__global__ __launch_bounds__(256, 2) void gemm_fused(
    const float* __restrict__ Af32,
    const unsigned short* __restrict__ Axh,
    const unsigned short* __restrict__ Bgh, const unsigned short* __restrict__ Bgl,
    const float* __restrict__ bias,
    unsigned short* __restrict__ outq, unsigned short* __restrict__ outk,
    unsigned short* __restrict__ outv, float* __restrict__ outp)
{
    __shared__ unsigned short sAh[64 * 128];
    __shared__ unsigned short sAl[SELQKV ? 64 * 128 : 64];   // unused for proj
    __shared__ unsigned short sBh[64 * 128];
    __shared__ unsigned short sBl[64 * 128];

    const int tid = threadIdx.x;
    const int m0 = blockIdx.x * 64;
    constexpr int NPH = SELQKV ? 6 : 2;

    // ---- stage A once ----
    if constexpr (SELQKV) {
#pragma unroll
        for (int it = 0; it < 8; ++it) {
            int idx = tid + it * 256;          // 0..2047 float4 chunks
            int row = idx >> 5;                // 0..63
            int c4  = idx & 31;
            float4 a = *(const float4*)(Af32 + (size_t)(m0 + row) * 128 + c4 * 4);
            int byte = (row * 256 + c4 * 8) ^ ((row & 7) << 4);
            ushort4 h, l;
            h.x = f2b(a.x); l.x = f2b(a.x - b2f(h.x));
            h.y = f2b(a.y); l.y = f2b(a.y - b2f(h.y));
            h.z = f2b(a.z); l.z = f2b(a.z - b2f(h.z));
            h.w = f2b(a.w); l.w = f2b(a.w - b2f(h.w));
            *(ushort4*)((char*)sAh + byte) = h;
            *(ushort4*)((char*)sAl + byte) = l;
        }
    } else {
#pragma unroll
        for (int it = 0; it < 4; ++it) {
            int chunk = it * 256 + tid;        // 0..1023
            int row = chunk >> 4, c16 = chunk & 15;
            int byte = (row * 256 + c16 * 16) ^ ((row & 7) << 4);
            size_t ga = (size_t)(m0 + row) * 128 + c16 * 8;
            *(uint4*)((char*)sAh + byte) = *(const uint4*)(Axh + ga);
        }
    }

    const int lane = tid & 63;
    const int w  = tid >> 6;
    const int wr = w >> 1, wc = w & 1;       // 2x2 waves -> 64x64
    const int fr  = lane & 15;
    const int kqb = (lane >> 4) * 16;        // k byte offset within 64B group
    const int cl = lane & 15;
    const int rq = lane >> 4;

    for (int ph = 0; ph < NPH; ++ph) {
        const int n0 = ph * 64;
        if (ph > 0) __syncthreads();         // prior mfma reads done before B overwrite
#pragma unroll
        for (int it = 0; it < 4; ++it) {
            int chunk = it * 256 + tid;      // 0..1023
            int row = chunk >> 4, c16 = chunk & 15;
            int byte = (row * 256 + c16 * 16) ^ ((row & 7) << 4);
            size_t gb = (size_t)(n0 + row) * 128 + c16 * 8;
            *(uint4*)((char*)sBh + byte) = *(const uint4*)(Bgh + gb);
            *(uint4*)((char*)sBl + byte) = *(const uint4*)(Bgl + gb);
        }
        __syncthreads();

        f32x4 acc[2][2];
#pragma unroll
        for (int i = 0; i < 2; ++i)
#pragma unroll
            for (int j = 0; j < 2; ++j) acc[i][j] = (f32x4){0.f, 0.f, 0.f, 0.f};

#pragma unroll
        for (int ks = 0; ks < 4; ++ks) {
            short8v ah[2], al[2], bh[2], bl[2];
#pragma unroll
            for (int mi = 0; mi < 2; ++mi) {
                int row = wr * 32 + mi * 16 + fr;
                int byte = (row * 256 + ks * 64 + kqb) ^ ((row & 7) << 4);
                ah[mi] = *(const short8v*)((const char*)sAh + byte);
                if constexpr (SELQKV)
                    al[mi] = *(const short8v*)((const char*)sAl + byte);
            }
#pragma unroll
            for (int ni = 0; ni < 2; ++ni) {
                int row = wc * 32 + ni * 16 + fr;
                int byte = (row * 256 + ks * 64 + kqb) ^ ((row & 7) << 4);
                bh[ni] = *(const short8v*)((const char*)sBh + byte);
                bl[ni] = *(const short8v*)((const char*)sBl + byte);
            }
#pragma unroll
            for (int mi = 0; mi < 2; ++mi)
#pragma unroll
                for (int ni = 0; ni < 2; ++ni) {
                    acc[mi][ni] = __builtin_amdgcn_mfma_f32_16x16x32_bf16(ah[mi], bh[ni], acc[mi][ni], 0, 0, 0);
                    acc[mi][ni] = __builtin_amdgcn_mfma_f32_16x16x32_bf16(ah[mi], bl[ni], acc[mi][ni], 0, 0, 0);
                    if constexpr (SELQKV)
                        acc[mi][ni] = __builtin_amdgcn_mfma_f32_16x16x32_bf16(al[mi], bh[ni], acc[mi][ni], 0, 0, 0);
                }
        }

        // ---- epilogue: C/D layout col=lane&15, row=4*(lane>>4)+reg ----
#pragma unroll
        for (int mi = 0; mi < 2; ++mi) {
#pragma unroll
            for (int reg = 0; reg < 4; ++reg) {
                int m = m0 + wr * 32 + mi * 16 + rq * 4 + reg;
                if constexpr (SELQKV) {
                    int b = m / 3136;
                    int r = m - b * 3136;
                    int y = r / 56;
                    int x = r - y * 56;
#pragma unroll
                    for (int ni = 0; ni < 2; ++ni) {
                        int nn = n0 + wc * 32 + ni * 16 + cl;   // 0..383
                        float val = acc[mi][ni][reg] + bias[nn];
                        int sel = nn >> 7;                      // 0=q 1=k 2=v
                        int nl = nn & 127;
                        int h = nl >> 5, d = nl & 31;
                        size_t oi = ((size_t)((b * NH + h) * 3136) + y * 56 + x) * 32 + d;
                        if (sel == 0)      outq[oi] = f2b(val * SCALE);   // q bf16
                        else if (sel == 1) outk[oi] = f2b(val);
                        else               outv[oi] = f2b(val);
                    }
                } else {
#pragma unroll
                    for (int ni = 0; ni < 2; ++ni) {
                        int nn = n0 + wc * 32 + ni * 16 + cl;
                        outp[(size_t)m * 128 + nn] = acc[mi][ni][reg] + bias[nn];
                    }
                }
            }
        }
    }
}

// ---------------------------------------------------------------------------
// Neighborhood attention v6c (round-14 structure; attn output now single
// bf16 — drops the lo-part computation and 6.4 MB of HBM writes):
// 4 threads per (pixel,head) d-chunk split, 256 thr, 8x8 tile, halo 14x14,
// grid 49x4x8.  V unpacked to f32 in LDS at staging (PV axpy = plain fmaf);
// K bf16 [pix][c]; dot as two 4-chains + add; q bf16 load hoisted (16B).
// LDS 36.8 KB -> 4 blocks/CU = 16 waves/CU.
// ---------------------------------------------------------------------------
__global__ __launch_bounds__(256, 4) void natt_k(
    const unsigned short* __restrict__ qs, const unsigned short* __restrict__ kb,
    const unsigned short* __restrict__ vb, const float* __restrict__ rpb,
    unsigned short* __restrict__ attn_h)
{
    __shared__ uint4 ks[196 * 4];                    // K bf16 [pix][c], 12544 B
    __shared__ __align__(16) float vfs[4][1572];     // V f32 c-sections, 25152 B

    const int tid = threadIdx.x;
    const int b = blockIdx.z, h = blockIdx.y;
    const int tyy = blockIdx.x / 7, txx = blockIdx.x - tyy * 7;  // 7x7 tiles
    const int y0 = tyy * 8, x0 = txx * 8;
    const int bh = b * NH + h;

    const int p = tid >> 2, c = tid & 3;   // quads 4-aligned -> DPP partners co-active
    const int py = p >> 3;
    const int pxx = p & 7;

    // hoisted q load (bf16, 16B) — unpack once per thread
    float q[8];
    {
        uint4 qv = *(const uint4*)(qs +
            ((size_t)(bh * 3136) + (y0 + py) * 56 + (x0 + pxx)) * 32 + c * 8);
        q[0] = blo(qv.x); q[1] = bhi(qv.x); q[2] = blo(qv.y); q[3] = bhi(qv.y);
        q[4] = blo(qv.z); q[5] = bhi(qv.z); q[6] = blo(qv.w); q[7] = bhi(qv.w);
    }

    const uint4* kg = (const uint4*)kb;  // 4 uint4 per pixel (32 bf16)
    const uint4* vg = (const uint4*)vb;
    for (int idx = tid; idx < 784; idx += 256) {   // 196 pix * 4 chunks
        int pix = idx >> 2, cc = idx & 3;
        int i = pix / 14;
        int j = pix - i * 14;
        int y = y0 + i - PAD;
        int x = x0 + j - PAD;
        uint4 zk = make_uint4(0u, 0u, 0u, 0u);
        uint4 zv = make_uint4(0u, 0u, 0u, 0u);
        if ((unsigned)y < 56u && (unsigned)x < 56u) {
            int g = ((bh * 3136) + y * 56 + x) * 4 + cc;
            zk = kg[g];
            zv = vg[g];
        }
        ks[idx] = zk;
        float4 f0, f1;
        f0.x = blo(zv.x); f0.y = bhi(zv.x); f0.z = blo(zv.y); f0.w = bhi(zv.y);
        f1.x = blo(zv.z); f1.y = bhi(zv.z); f1.z = blo(zv.w); f1.w = bhi(zv.w);
        float* vd = &vfs[cc][pix * 8];
        *(float4*)(vd)     = f0;
        *(float4*)(vd + 4) = f1;
    }
    __syncthreads();

    float acc[8];
#pragma unroll
    for (int d = 0; d < 8; ++d) acc[d] = 0.f;
    float l = 0.f;

    const float* rph = rpb + h * 49;       // uniform index -> scalar loads
    const float* vbase = &vfs[c][0];

#pragma unroll
    for (int dy = 0; dy < 7; ++dy) {
        int rowpix = (py + dy) * 14 + pxx;
#pragma unroll
        for (int dx = 0; dx < 7; ++dx) {
            int pix = rowpix + dx;
            float s  = dot8v(q, ks[pix * 4 + c]);
            float sf = quad_sum(s) + rph[dy * 7 + dx];
            float e  = __expf(sf);
            l += e;
            const float* vv = vbase + pix * 8;
            float4 v0 = *(const float4*)(vv);
            float4 v1 = *(const float4*)(vv + 4);
            acc[0] = fmaf(e, v0.x, acc[0]); acc[1] = fmaf(e, v0.y, acc[1]);
            acc[2] = fmaf(e, v0.z, acc[2]); acc[3] = fmaf(e, v0.w, acc[3]);
            acc[4] = fmaf(e, v1.x, acc[4]); acc[5] = fmaf(e, v1.y, acc[5]);
            acc[6] = fmaf(e, v1.z, acc[6]); acc[7] = fmaf(e, v1.w, acc[7]);
        }
    }

    float rl = 1.0f / l;

    // pack 8 dims -> bf16 uint4, single b128 store
    unsigned short hv[8];
#pragma unroll
    for (int d = 0; d < 8; ++d) hv[d] = f2b(acc[d] * rl);
    uint4 uh;
    uh.x = (unsigned)hv[0] | ((unsigned)hv[1] << 16);
    uh.y = (unsigned)hv[2] | ((unsigned)hv[3] << 16);
    uh.z = (unsigned)hv[4] | ((unsigned)hv[5] << 16);
    uh.w = (unsigned)hv[6] | ((unsigned)hv[7] << 16);

    size_t base = ((size_t)(b * 3136) + (y0 + py) * 56 + (x0 + pxx)) * 128 + h * 32 + c * 8;
    *(uint4*)(attn_h + base) = uh;
}

extern "C" void kernel_launch(void* const* d_in, const int* in_sizes, int n_in,
                              void* d_out, int out_size, void* d_ws, size_t ws_size,
                              hipStream_t stream)
{
    const float* x     = (const float*)d_in[0];
    const float* Wqkv  = (const float*)d_in[1];
    const float* bqkv  = (const float*)d_in[2];
    const float* rpb   = (const float*)d_in[3];
    const float* Wproj = (const float*)d_in[4];
    const float* bproj = (const float*)d_in[5];
    float* out = (float*)d_out;

    char* ws = (char*)d_ws;
    unsigned short* qsb  = (unsigned short*)(ws + QS_OFF);   // q bf16 (pre-scaled)
    unsigned short* kbuf = (unsigned short*)(ws + K_OFF);
    unsigned short* vbuf = (unsigned short*)(ws + V_OFF);
    unsigned short* xh   = (unsigned short*)(ws + XH_OFF);   // attn bf16 (from natt)
    unsigned short* wqh  = (unsigned short*)(ws + WQH_OFF);
    unsigned short* wql  = (unsigned short*)(ws + WQL_OFF);
    unsigned short* wph  = (unsigned short*)(ws + WPH_OFF);
    unsigned short* wpl  = (unsigned short*)(ws + WPL_OFF);

    // 0) split weights into (hi,lo) bf16 (tiny)
    split_k<<<64, 256, 0, stream>>>(Wqkv, Wproj, wqh, wql, wph, wpl);

    // 1) QKV projection: 392 m-blocks, 6 internal n-phases (A staged once)
    gemm_fused<1><<<392, 256, 0, stream>>>(x, nullptr, wqh, wql, bqkv,
                                           qsb, kbuf, vbuf, nullptr);

    // 2) neighborhood attention (v6c): 49 tiles x 4 heads x 8 batch, 256 thr
    natt_k<<<dim3(49, NH, 8), 256, 0, stream>>>(qsb, kbuf, vbuf, rpb, xh);

    // 3) output projection: 392 m-blocks, 2 internal n-phases, A = bf16 attn
    gemm_fused<0><<<392, 256, 0, stream>>>(nullptr, xh, wph, wpl, bproj,
                                           nullptr, nullptr, nullptr, out);
}